// Round 7
// baseline (56.176 us; speedup 1.0000x reference)
//
#include <hip/hip_runtime.h>

// 4-level lifting wavelet, fully fused, WAVE-AUTONOMOUS (zero block barriers).
// Each wave64 owns one 1024-elem chunk + 256-elem circular left halo in a
// private 1280-float LDS region (5 KB). R6 failed: same-wave LDS WAR/RAW
// ordering without waits is NOT safe (first design to rely on it). R7 adds
// explicit wave-local fences: s_waitcnt lgkmcnt(0) + sched_barrier(0)
//  - between each level's LDS read phase and its (aliasing) write phase (WAR)
//  - after each write phase, before downstream LDS readers (RAW).
// Still zero __syncthreads: waves flow stage->L0->z0->L1->...->z4
// independently; 8 blocks/CU (20 KB LDS) = 32 waves/CU.
#define BS    256
#define WC    1024
#define HALO  256
#define NN    65536
#define WFL   1280   // per-wave LDS floats

#define WAVE_FENCE() do { \
    asm volatile("s_waitcnt lgkmcnt(0)" ::: "memory"); \
    __builtin_amdgcn_sched_barrier(0); \
  } while (0)

// One lifting level over NPAIRS pairs at wA[inOff+2p]; lane owns pairs
// [M*lane, M*lane+M), reads window [M*lane-8, ...) (8-pair recompute halo),
// writes avg->wA[avgOff+p], det->wA[detOff+p] (may alias input region).
template<int M, int NPAIRS>
__device__ __forceinline__ void wave_lift(float* wA, int inOff, int avgOff,
                                          int detOff,
                                          const float* __restrict__ P6,
                                          const float* __restrict__ U6,
                                          int lane) {
  constexpr int W = M + 8;
  float in[2 * W];
  const int p0 = M * lane - 8;
#pragma unroll
  for (int i = 0; i < W; ++i) {
    int p = p0 + i;
    p = p < 0 ? 0 : (p >= NPAIRS ? NPAIRS - 1 : p);
    float2 v = *(const float2*)&wA[inOff + 2 * p];
    in[2 * i] = v.x;
    in[2 * i + 1] = v.y;
  }
  const float P0 = P6[0], P1 = P6[1], P2 = P6[2], P3 = P6[3], P4 = P6[4], P5 = P6[5];
  const float U0 = U6[0], U1 = U6[1], U2 = U6[2], U3 = U6[3], U4 = U6[4], U5 = U6[5];
  WAVE_FENCE();   // WAR: all reads returned before in-place writes issue
  float e1 = 0, e2 = 0, d1 = 0, d2 = 0, a1 = 0, a2 = 0, f1 = 0, f2 = 0;
#pragma unroll
  for (int i = 0; i < W; ++i) {
    float e0 = in[2 * i], o0 = in[2 * i + 1];
    float d0 = o0 - (P0 * e0 + P1 * e1 + P2 * e2);
    float a0 = e0 + (U0 * d0 + U1 * d1 + U2 * d2);
    float f0 = d0 - (P3 * a0 + P4 * a1 + P5 * a2);
    float b0 = a0 + (U3 * f0 + U4 * f1 + U5 * f2);
    if (i >= 8) {
      int p = p0 + i;             // >= 0 here
      if (p < NPAIRS) {
        wA[avgOff + p] = b0;
        wA[detOff + p] = f0;
      }
    }
    e2 = e1; e1 = e0; d2 = d1; d1 = d0; a2 = a1; a1 = a0; f2 = f1; f1 = f0;
  }
  WAVE_FENCE();   // RAW: writes committed before downstream LDS reads
}

__global__ __launch_bounds__(BS)
void wavelet_fused_kernel(const float* __restrict__ x,
                          const float* __restrict__ Pc,
                          const float* __restrict__ Uc,
                          float* __restrict__ out) {
  __shared__ __align__(16) float A[4 * WFL];   // 20 KB

  const int tid  = threadIdx.x;
  const int wave = tid >> 6;
  const int lane = tid & 63;
  const int gc   = blockIdx.x * 4 + wave;   // wave-chunk 0..63
  const int row  = blockIdx.y;              // row 0..511
  float* wA = A + wave * WFL;

  // ---- stage WC + HALO = 1280 floats (320 float4) direct to LDS ----
  const float4* x4 = (const float4*)(x + (size_t)row * NN);
  const int base4 = ((gc * WC - HALO) & (NN - 1)) >> 2;
#pragma unroll
  for (int s = 0; s < 5; ++s) {
    const float4* g = &x4[(base4 + s * 64 + lane) & (NN / 4 - 1)];
    __builtin_amdgcn_global_load_lds(
        (const __attribute__((address_space(1))) void*)g,
        (__attribute__((address_space(3))) void*)&wA[s * 256], 16, 0, 0);
  }
  asm volatile("s_waitcnt vmcnt(0)" ::: "memory");
  __builtin_amdgcn_sched_barrier(0);

  // ---- L0: 640 pairs [0,1280) -> avg [0,640), det [640,1280) ----
  wave_lift<10, 640>(wA, 0, 0, 640, Pc, Uc, lane);
  {  // z0: avg pairs [128,640) -> 512 floats
    float4* d = (float4*)(out + (size_t)row * 32768 + gc * 512);
    d[lane]      = *(const float4*)&wA[128 + 4 * lane];
    d[lane + 64] = *(const float4*)&wA[384 + 4 * lane];
  }

  // ---- L1: 320 pairs [640,1280) -> avg [640,960), det [960,1280) ----
  wave_lift<5, 320>(wA, 640, 640, 960, Pc + 6, Uc + 6, lane);
  {  // z1: avg pairs [64,320) -> 256 floats
    float4* d = (float4*)(out + 16777216 + (size_t)row * 16384 + gc * 256);
    d[lane] = *(const float4*)&wA[704 + 4 * lane];
  }

  // ---- L2: 160 pairs [960,1280) -> avg [960,1120), det [1120,1280) ----
  wave_lift<3, 160>(wA, 960, 960, 1120, Pc + 12, Uc + 12, lane);
  {  // z2: avg pairs [32,160) -> 128 floats
    float2* d = (float2*)(out + 25165824 + (size_t)row * 8192 + gc * 128);
    d[lane] = *(const float2*)&wA[992 + 2 * lane];
  }

  // ---- L3: 80 pairs [1120,1280) -> avg [1120,1200), det [1200,1280) ----
  wave_lift<2, 80>(wA, 1120, 1120, 1200, Pc + 18, Uc + 18, lane);
  {  // z3/z4: pairs [16,80) -> 64 floats each
    float* d3 = out + 29360128 + (size_t)row * 4096 + gc * 64;
    float* d4 = out + 31457280 + (size_t)row * 4096 + gc * 64;
    d3[lane] = wA[1136 + lane];
    d4[lane] = wA[1216 + lane];
  }
}

extern "C" void kernel_launch(void* const* d_in, const int* in_sizes, int n_in,
                              void* d_out, int out_size, void* d_ws, size_t ws_size,
                              hipStream_t stream) {
  const float* x  = (const float*)d_in[0];
  const float* Pc = (const float*)d_in[1];
  const float* Uc = (const float*)d_in[2];
  float* out = (float*)d_out;

  dim3 grid(NN / WC / 4, 512, 1);   // 16 x 512 blocks, 4 waves each
  dim3 block(BS, 1, 1);
  wavelet_fused_kernel<<<grid, block, 0, stream>>>(x, Pc, Uc, out);
}

// Round 8
// 54.126 us; speedup vs baseline: 1.0379x; 1.0379x over previous
//
#include <hip/hip_runtime.h>

// 4-level lifting wavelet, fully fused. R8 design:
//  - M=4 pairs/thread => each thread's 4 avg values = one float4, coalesced
//    across lanes => ALL z-outputs stored directly from registers (no LDS
//    round-trip, no store phases). 8-pair recompute halo per 4-pair slot.
//  - L0 reads x DIRECTLY from global (per-thread contiguous float4 windows;
//    L1$ absorbs the 3x lane overlap) => no input staging, no halo staging.
//  - LDS carries only the det chains: Y1 (det0/det2), Y2 (det1), ping-pong.
//    Padded layout addr(i) = 9*(i>>3) + (i&7) => b128 reads at 36B lane
//    stride = conflict-free (vs 16-way at 32B).
//  - 3 __syncthreads total. 14.7 KB LDS, __launch_bounds__(256,8).
// Validity: L0 windows are always real data (circular wrap) => det0 exact
// everywhere; detK exact for pair >= {0,8,12,14}; chunk ownership margin
// (128 pairs at L0 scale) cascades to {128,64,32,16} >= needed. Discards in
// float4-slot units: 32/16/8/4.
#define BS 256
#define NN 65536

__device__ __forceinline__ void lift12(const float* __restrict__ w,
                                       float P0, float P1, float P2,
                                       float P3, float P4, float P5,
                                       float U0, float U1, float U2,
                                       float U3, float U4, float U5,
                                       float4& av, float4& dv) {
  float e1 = 0, e2 = 0, d1 = 0, d2 = 0, a1 = 0, a2 = 0, f1 = 0, f2 = 0;
  float avv[4], dvv[4];
#pragma unroll
  for (int i = 0; i < 12; ++i) {
    float e0 = w[2 * i], o0 = w[2 * i + 1];
    float d0 = o0 - (P0 * e0 + P1 * e1 + P2 * e2);
    float a0 = e0 + (U0 * d0 + U1 * d1 + U2 * d2);
    float f0 = d0 - (P3 * a0 + P4 * a1 + P5 * a2);
    float b0 = a0 + (U3 * f0 + U4 * f1 + U5 * f2);
    if (i >= 8) { avv[i - 8] = b0; dvv[i - 8] = f0; }
    e2 = e1; e1 = e0; d2 = d1; d1 = d0; a2 = a1; a1 = a0; f2 = f1; f1 = f0;
  }
  av = make_float4(avv[0], avv[1], avv[2], avv[3]);
  dv = make_float4(dvv[0], dvv[1], dvv[2], dvv[3]);
}

// padded det write slot address (float4-aligned half-group)
#define DSTW(s) (9 * ((s) >> 1) + 4 * ((s) & 1))

__global__ __launch_bounds__(BS, 8)
void wavelet_fused_kernel(const float* __restrict__ x,
                          const float* __restrict__ Pc,
                          const float* __restrict__ Uc,
                          float* __restrict__ out) {
  __shared__ __align__(16) float Y1[2448];   // det0 (272 groups), later det2
  __shared__ __align__(16) float Y2[1224];   // det1 (136 groups)

  const int tid = threadIdx.x;
  const int cx  = blockIdx.x;       // chunk 0..15
  const int row = blockIdx.y;       // row 0..511
  const int S   = cx * 4096;
  const int mask4 = NN / 4 - 1;

  // ---- L0: global -> (z0 direct, det0 -> Y1) ----
  {
    const float4* x4 = (const float4*)(x + (size_t)row * NN);
    float4* z0 = (float4*)out + (size_t)row * 8192 + (S >> 3);
    const float p0 = Pc[0], p1 = Pc[1], p2 = Pc[2], p3 = Pc[3], p4 = Pc[4], p5 = Pc[5];
    const float u0 = Uc[0], u1 = Uc[1], u2 = Uc[2], u3 = Uc[3], u4 = Uc[4], u5 = Uc[5];
    for (int s = tid; s < 544; s += BS) {
      float w[24];
      const int b4 = (S - 272 + 8 * s) >> 2;   // exact (multiple of 4), may wrap
#pragma unroll
      for (int j = 0; j < 6; ++j) {
        float4 v = x4[(b4 + j) & mask4];
        w[4 * j + 0] = v.x; w[4 * j + 1] = v.y;
        w[4 * j + 2] = v.z; w[4 * j + 3] = v.w;
      }
      float4 av, dv;
      lift12(w, p0, p1, p2, p3, p4, p5, u0, u1, u2, u3, u4, u5, av, dv);
      *(float4*)&Y1[DSTW(s)] = dv;
      if (s >= 32) z0[s - 32] = av;
    }
  }
  __syncthreads();   // (1)

  // ---- L1: Y1 -> (z1 direct, det1 -> Y2) ----
  {
    float4* z1 = (float4*)out + 4194304 + row * 4096 + (S >> 4);
    const float p0 = Pc[6], p1 = Pc[7], p2 = Pc[8], p3 = Pc[9], p4 = Pc[10], p5 = Pc[11];
    const float u0 = Uc[6], u1 = Uc[7], u2 = Uc[8], u3 = Uc[9], u4 = Uc[10], u5 = Uc[11];
    for (int s = tid; s < 272; s += BS) {
      float w[24];
#pragma unroll
      for (int j = 0; j < 3; ++j) {
        int g = s - 2 + j; g = g < 0 ? 0 : g;
        float4 v0 = *(const float4*)&Y1[9 * g];
        float4 v1 = *(const float4*)&Y1[9 * g + 4];
        w[8 * j + 0] = v0.x; w[8 * j + 1] = v0.y; w[8 * j + 2] = v0.z; w[8 * j + 3] = v0.w;
        w[8 * j + 4] = v1.x; w[8 * j + 5] = v1.y; w[8 * j + 6] = v1.z; w[8 * j + 7] = v1.w;
      }
      float4 av, dv;
      lift12(w, p0, p1, p2, p3, p4, p5, u0, u1, u2, u3, u4, u5, av, dv);
      *(float4*)&Y2[DSTW(s)] = dv;
      if (s >= 16) z1[s - 16] = av;
    }
  }
  __syncthreads();   // (2)

  // ---- L2: Y2 -> (z2 direct, det2 -> Y1 reuse) ----
  {
    float4* z2 = (float4*)out + 6291456 + row * 2048 + (S >> 5);
    const float p0 = Pc[12], p1 = Pc[13], p2 = Pc[14], p3 = Pc[15], p4 = Pc[16], p5 = Pc[17];
    const float u0 = Uc[12], u1 = Uc[13], u2 = Uc[14], u3 = Uc[15], u4 = Uc[16], u5 = Uc[17];
    for (int s = tid; s < 136; s += BS) {
      float w[24];
#pragma unroll
      for (int j = 0; j < 3; ++j) {
        int g = s - 2 + j; g = g < 0 ? 0 : g;
        float4 v0 = *(const float4*)&Y2[9 * g];
        float4 v1 = *(const float4*)&Y2[9 * g + 4];
        w[8 * j + 0] = v0.x; w[8 * j + 1] = v0.y; w[8 * j + 2] = v0.z; w[8 * j + 3] = v0.w;
        w[8 * j + 4] = v1.x; w[8 * j + 5] = v1.y; w[8 * j + 6] = v1.z; w[8 * j + 7] = v1.w;
      }
      float4 av, dv;
      lift12(w, p0, p1, p2, p3, p4, p5, u0, u1, u2, u3, u4, u5, av, dv);
      *(float4*)&Y1[DSTW(s)] = dv;
      if (s >= 8) z2[s - 8] = av;
    }
  }
  __syncthreads();   // (3)

  // ---- L3: Y1 -> (z3, z4 direct) ----
  {
    float4* z3 = (float4*)out + 7340032 + row * 1024 + (S >> 6);
    float4* z4 = (float4*)out + 7864320 + row * 1024 + (S >> 6);
    const float p0 = Pc[18], p1 = Pc[19], p2 = Pc[20], p3 = Pc[21], p4 = Pc[22], p5 = Pc[23];
    const float u0 = Uc[18], u1 = Uc[19], u2 = Uc[20], u3 = Uc[21], u4 = Uc[22], u5 = Uc[23];
    for (int s = tid; s < 68; s += BS) {
      float w[24];
#pragma unroll
      for (int j = 0; j < 3; ++j) {
        int g = s - 2 + j; g = g < 0 ? 0 : g;
        float4 v0 = *(const float4*)&Y1[9 * g];
        float4 v1 = *(const float4*)&Y1[9 * g + 4];
        w[8 * j + 0] = v0.x; w[8 * j + 1] = v0.y; w[8 * j + 2] = v0.z; w[8 * j + 3] = v0.w;
        w[8 * j + 4] = v1.x; w[8 * j + 5] = v1.y; w[8 * j + 6] = v1.z; w[8 * j + 7] = v1.w;
      }
      float4 av, dv;
      lift12(w, p0, p1, p2, p3, p4, p5, u0, u1, u2, u3, u4, u5, av, dv);
      if (s >= 4) { z3[s - 4] = av; z4[s - 4] = dv; }
    }
  }
}

extern "C" void kernel_launch(void* const* d_in, const int* in_sizes, int n_in,
                              void* d_out, int out_size, void* d_ws, size_t ws_size,
                              hipStream_t stream) {
  const float* x  = (const float*)d_in[0];
  const float* Pc = (const float*)d_in[1];
  const float* Uc = (const float*)d_in[2];
  float* out = (float*)d_out;

  dim3 grid(16, 512, 1);
  dim3 block(BS, 1, 1);
  wavelet_fused_kernel<<<grid, block, 0, stream>>>(x, Pc, Uc, out);
}

// Round 9
// 49.744 us; speedup vs baseline: 1.1293x; 1.0881x over previous
//
#include <hip/hip_runtime.h>

// 4-level lifting wavelet, fully fused. R9: small-block high-occupancy variant.
//  - BS=128 (2 waves), CHUNK=2048, in-place LDS A[2304] = 9.2 KB
//    -> 16 blocks/CU = 32 waves/CU (100% wave slots), 16384 blocks total.
//  - global_load_lds staging (R5's win) of chunk + 256 circular halo.
//  - Per level: lift_read (window->regs, 8-pair recompute halo) / barrier /
//    lift_write (in-place avg+det). Every z-store overlaps the next level's
//    lift_read on the other thread-half; 9 cheap 2-wave barriers.
//  - __launch_bounds__(128,8) caps VGPR at 64 for 8 waves/SIMD.
#define BS    128
#define CHUNK 2048
#define HALO  256
#define NN    65536
#define LDSF  2304   // CHUNK + HALO floats

template<int M, int NP>
__device__ __forceinline__ void lift_read(const float* __restrict__ A, int inOff,
                                          int t, float* __restrict__ in) {
  const int p0 = M * t - 8;
#pragma unroll
  for (int i = 0; i < M + 8; ++i) {
    int p = p0 + i;
    p = p < 0 ? 0 : (p >= NP ? NP - 1 : p);
    float2 v = *(const float2*)&A[inOff + 2 * p];
    in[2 * i] = v.x;
    in[2 * i + 1] = v.y;
  }
}

template<int M, int NP>
__device__ __forceinline__ void lift_write(float* __restrict__ A, int avgOff,
                                           int detOff, int t,
                                           const float* __restrict__ in,
                                           const float* __restrict__ P6,
                                           const float* __restrict__ U6) {
  const float P0 = P6[0], P1 = P6[1], P2 = P6[2], P3 = P6[3], P4 = P6[4], P5 = P6[5];
  const float U0 = U6[0], U1 = U6[1], U2 = U6[2], U3 = U6[3], U4 = U6[4], U5 = U6[5];
  const int p0 = M * t - 8;
  float e1 = 0, e2 = 0, d1 = 0, d2 = 0, a1 = 0, a2 = 0, f1 = 0, f2 = 0;
#pragma unroll
  for (int i = 0; i < M + 8; ++i) {
    float e0 = in[2 * i], o0 = in[2 * i + 1];
    float d0 = o0 - (P0 * e0 + P1 * e1 + P2 * e2);
    float a0 = e0 + (U0 * d0 + U1 * d1 + U2 * d2);
    float f0 = d0 - (P3 * a0 + P4 * a1 + P5 * a2);
    float b0 = a0 + (U3 * f0 + U4 * f1 + U5 * f2);
    if (i >= 8) {
      int p = p0 + i;               // >= 0
      if (p < NP) { A[avgOff + p] = b0; A[detOff + p] = f0; }
    }
    e2 = e1; e1 = e0; d2 = d1; d1 = d0; a2 = a1; a1 = a0; f2 = f1; f1 = f0;
  }
}

__global__ __launch_bounds__(BS, 8)
void wavelet_fused_kernel(const float* __restrict__ x,
                          const float* __restrict__ Pc,
                          const float* __restrict__ Uc,
                          float* __restrict__ out) {
  __shared__ __align__(16) float A[LDSF];   // 9.2 KB

  const int tid  = threadIdx.x;
  const int wave = tid >> 6;
  const int lane = tid & 63;
  const int cx   = blockIdx.x;    // chunk 0..31
  const int row  = blockIdx.y;    // row 0..511
  const int S    = cx * CHUNK;

  // ---- stage CHUNK + HALO = 2304 floats (576 float4 = 9 wave-slices) ----
  {
    const float4* x4 = (const float4*)(x + (size_t)row * NN);
    const int base4 = ((S - HALO) & (NN - 1)) >> 2;
    for (int s = wave; s < 9; s += 2) {
      const float4* g = &x4[(base4 + s * 64 + lane) & (NN / 4 - 1)];
      __builtin_amdgcn_global_load_lds(
          (const __attribute__((address_space(1))) void*)g,
          (__attribute__((address_space(3))) void*)&A[s * 256], 16, 0, 0);
    }
  }
  __syncthreads();   // (1)

  float4* z0 = (float4*)out + (size_t)row * 8192 + (S >> 3);
  float4* z1 = (float4*)out + 4194304 + row * 4096 + (S >> 4);
  float4* z2 = (float4*)out + 6291456 + row * 2048 + (S >> 5);
  float4* z3 = (float4*)out + 7340032 + row * 1024 + (S >> 6);
  float4* z4 = (float4*)out + 7864320 + row * 1024 + (S >> 6);

  // ---- L0: 1152 pairs in [0,2304) -> avg [0,1152), det [1152,2304) ----
  {
    float in0[34];
    lift_read<9, 1152>(A, 0, tid, in0);
    __syncthreads();   // (2) WAR
    lift_write<9, 1152>(A, 0, 1152, tid, in0, Pc, Uc);
  }
  __syncthreads();     // (3)

  // ---- z0 store (threads 64-127) || L1 read (threads 0-63) ----
  float in1[34];
  if (tid < 64) {
    lift_read<9, 576>(A, 1152, tid, in1);
  } else {
    const int t = tid - 64;
#pragma unroll
    for (int k = 0; k < 4; ++k) z0[t + 64 * k] = *(const float4*)&A[128 + 4 * (t + 64 * k)];
  }
  __syncthreads();     // (4) z0 reads done + L1 WAR
  if (tid < 64) lift_write<9, 576>(A, 1152, 1728, tid, in1, Pc + 6, Uc + 6);
  __syncthreads();     // (5)

  // ---- z1 store || L2 read ----
  float in2[26];
  if (tid < 64) {
    lift_read<5, 288>(A, 1728, tid, in2);
  } else {
    const int t = tid - 64;
#pragma unroll
    for (int k = 0; k < 2; ++k) z1[t + 64 * k] = *(const float4*)&A[1216 + 4 * (t + 64 * k)];
  }
  __syncthreads();     // (6)
  if (tid < 64) lift_write<5, 288>(A, 1728, 2016, tid, in2, Pc + 12, Uc + 12);
  __syncthreads();     // (7)

  // ---- z2 store || L3 read ----
  float in3[22];
  if (tid < 64) {
    lift_read<3, 144>(A, 2016, tid, in3);
  } else {
    const int t = tid - 64;
    z2[t] = *(const float4*)&A[1760 + 4 * t];
  }
  __syncthreads();     // (8)
  if (tid < 64) lift_write<3, 144>(A, 2016, 2160, tid, in3, Pc + 18, Uc + 18);
  __syncthreads();     // (9)

  // ---- z3/z4 direct ----
  if (tid < 32)                     z3[tid]      = *(const float4*)&A[2032 + 4 * tid];
  else if (tid >= 64 && tid < 96)   z4[tid - 64] = *(const float4*)&A[2176 + 4 * (tid - 64)];
}

extern "C" void kernel_launch(void* const* d_in, const int* in_sizes, int n_in,
                              void* d_out, int out_size, void* d_ws, size_t ws_size,
                              hipStream_t stream) {
  const float* x  = (const float*)d_in[0];
  const float* Pc = (const float*)d_in[1];
  const float* Uc = (const float*)d_in[2];
  float* out = (float*)d_out;

  dim3 grid(NN / CHUNK, 512, 1);   // 32 x 512 = 16384 blocks
  dim3 block(BS, 1, 1);
  wavelet_fused_kernel<<<grid, block, 0, stream>>>(x, Pc, Uc, out);
}